// Round 7
// baseline (543.266 us; speedup 1.0000x reference)
//
#include <hip/hip_runtime.h>

// ---------------- problem constants ----------------
#define F2      254
#define NPIX    (F2 * F2)        // 64516 conv2 output pixels
#define NANCH   (NPIX * 9)       // 580644 anchors
#define KGT     16
#define GWC     (1.0f / 1024.0f) // gw == gh == 1/IMG

// ---------------- static device storage: EXACTLY the r2 set (the module that ran) ----------------
__device__ unsigned short g_feats[256 * 256 * 128];  // conv1 out, bf16, 16.78 MB
__device__ unsigned short g_cls[NPIX * 9];           // cls logits bf16
__device__ unsigned short g_reg[NPIX * 36];          // reg preds bf16
__device__ float          g_W2[1152 * 48];           // combined weights (45 padded to 48)
__device__ float          g_b2[48];
__device__ float          g_acc[4];                  // bce_sum, sel_cnt, box_sum, pos_cnt
__device__ unsigned       g_keys[KGT];               // monotone-encoded gt-max

__device__ __forceinline__ float b2f(unsigned short h) {
    return __uint_as_float(((unsigned)h) << 16);
}
__device__ __forceinline__ unsigned short f2b(float f) {
    unsigned u = __float_as_uint(f);
    unsigned r = (u + 0x7FFFu + ((u >> 16) & 1u)) >> 16;
    return (unsigned short)r;
}
__device__ __forceinline__ float blo(unsigned u) { return __uint_as_float(u << 16); }
__device__ __forceinline__ float bhi(unsigned u) { return __uint_as_float(u & 0xFFFF0000u); }

// ---------------- shared IoU core: ONE code instance -> bit-exact across passes ----------------
__device__ __attribute__((noinline)) void anchor_ious(int n, const float* __restrict__ gt,
                                                      float* __restrict__ v) {
    int w_idx = n / (F2 * 9);
    int rem = n - w_idx * (F2 * 9);
    int h_idx = rem / 9;
    int a = rem - h_idx * 9;
    int ri = a / 3, si = a - ri * 3;
    float rat = (ri == 0) ? 0.5f : (ri == 1) ? 1.0f : 2.0f;
    float scl = (si == 0) ? 0.2f : (si == 1) ? 0.4f : 0.7f;
    float rs = sqrtf(rat);
    float hw = scl * rs * 0.5f;
    float hh = scl / rs * 0.5f;
    float cx = (float)w_idx * (1.0f / 254.0f);
    float cy = (float)h_idx * (1.0f / 254.0f);
    float x1 = cx - hw, y1 = cy - hh, x2 = cx + hw, y2 = cy + hh;
    bool inside = (x1 >= 0.0f) && (y1 >= 0.0f) && (x2 < 1.0f) && (y2 < 1.0f);
    float s1 = (x2 - x1 + GWC) * (y2 - y1 + GWC);
    for (int k = 0; k < KGT; ++k) {
        float gx1 = gt[k * 4 + 0], gy1 = gt[k * 4 + 1];
        float gx2 = gt[k * 4 + 2], gy2 = gt[k * 4 + 3];
        float s2 = (gx2 - gx1 + GWC) * (gy2 - gy1 + GWC);
        float xa = fmaxf(x1, gx1), ya = fmaxf(y1, gy1);
        float xb = fminf(x2, gx2), yb = fminf(y2, gy2);
        float iw = fmaxf(xb - xa + GWC, 0.0f);
        float ih = fmaxf(yb - ya + GWC, 0.0f);
        float inter = iw * ih;
        float iou = inter / (s1 + s2 - inter);
        v[k] = inside ? iou : -1.0f;
    }
}

// ---------------- init: zero accumulators, keys=enc(-1), dual-format out sentinel ----------------
__global__ void k_init(unsigned* out) {
    int t = threadIdx.x;
    if (t < 4) g_acc[t] = 0.0f;
    if (t >= 4 && t < 4 + KGT) g_keys[t - 4] = 0x407FFFFFu; // enc(-1.0f)
    if (t == 32) out[0] = 0x3F803F80u; // sentinel: bf16 1.0 in low16
}

// ---------------- conv1: 1024x1024x3 (fp32) -> 256x256x128 bf16, 4x4 stride 4 ----------------
__global__ __launch_bounds__(256) void k_conv1(const float* __restrict__ img,
                                               const float* __restrict__ Wb,
                                               const float* __restrict__ bb) {
    int t = threadIdx.x;
    int g = t & 31;   // oc group -> oc = 4g..4g+3
    int mi = t >> 5;  // pixel within block
    int p = blockIdx.x * 8 + mi;
    int oy = p >> 8, ox = p & 255;
    const float* ib = img + ((size_t)oy * 4 * 1024 + (size_t)ox * 4) * 3;
    float4 acc = *(const float4*)(bb + g * 4);
#pragma unroll
    for (int r = 0; r < 4; ++r) {
#pragma unroll
        for (int q = 0; q < 3; ++q) {
            float4 pf = *(const float4*)(ib + (size_t)r * 3072 + q * 4);
            float pv[4] = {pf.x, pf.y, pf.z, pf.w};
#pragma unroll
            for (int e = 0; e < 4; ++e) {
                float4 wv4 = *(const float4*)(Wb + (size_t)((r * 3 + q) * 4 + e) * 128 + g * 4);
                acc.x = fmaf(pv[e], wv4.x, acc.x);
                acc.y = fmaf(pv[e], wv4.y, acc.y);
                acc.z = fmaf(pv[e], wv4.z, acc.z);
                acc.w = fmaf(pv[e], wv4.w, acc.w);
            }
        }
    }
    ushort4 o;
    o.x = f2b(acc.x); o.y = f2b(acc.y); o.z = f2b(acc.z); o.w = f2b(acc.w);
    *(ushort4*)(g_feats + (size_t)p * 128 + g * 4) = o;
}

// ---------------- W2 precombine: W2[k][o] = sum_oc Wi[k][oc]*Wcr[oc][o] ----------------
__global__ __launch_bounds__(256) void k_w2(const float* __restrict__ Wi,
                                            const float* __restrict__ bi,
                                            const float* __restrict__ Wc,
                                            const float* __restrict__ bc,
                                            const float* __restrict__ Wr,
                                            const float* __restrict__ br) {
    int tid = blockIdx.x * 256 + threadIdx.x;
    if (tid < 1152 * 48) {
        int k = tid / 48;
        int o = tid - k * 48;
        if (o >= 45) { g_W2[tid] = 0.0f; return; }
        float acc = 0.0f;
        for (int oc = 0; oc < 256; ++oc) {
            float wc = (o < 9) ? Wc[oc * 9 + o] : Wr[oc * 36 + (o - 9)];
            acc = fmaf(Wi[k * 256 + oc], wc, acc);
        }
        g_W2[tid] = acc;
    } else if (tid < 1152 * 48 + 45) {
        int o = tid - 1152 * 48;
        float acc = (o < 9) ? bc[o] : br[o - 9];
        for (int oc = 0; oc < 256; ++oc) {
            float wc = (o < 9) ? Wc[oc * 9 + o] : Wr[oc * 36 + (o - 9)];
            acc = fmaf(bi[oc], wc, acc);
        }
        g_b2[o] = acc;
    } else if (tid < 1152 * 48 + 48) {
        g_b2[tid - 1152 * 48] = 0.0f;
    }
}

// ---------------- combined conv: feats -> cls (NPIX x 9), reg (NPIX x 36) ----------------
// GEMM M=NPIX, K=1152, N=45. block=128 thr = 64 pixels x 2 ch-parts; waves split o 23/22.
__global__ __launch_bounds__(128) void k_convC() {
    __shared__ float At[16 * 68];
    int t = threadIdx.x;
    int lane = t & 63;
    int wv = t >> 6;
    int oBase = __builtin_amdgcn_readfirstlane(wv ? 23 : 0);
    int nO = wv ? 22 : 23;
    int gm = blockIdx.x * 64 + lane;
    bool valid = gm < NPIX;

    int part = t & 1;      // 8-channel group within 16-ch chunk
    int mL = t >> 1;       // pixel column 0..63
    int sp = blockIdx.x * 64 + mL;
    sp = min(sp, NPIX - 1);
    int py = sp / F2, px = sp - py * F2;

    float acc[23];
#pragma unroll
    for (int o = 0; o < 23; ++o) acc[o] = 0.0f;

    for (int pos = 0; pos < 9; ++pos) {
        int ky = pos / 3, kx = pos - (pos / 3) * 3;
        size_t fb = ((size_t)(py + ky) * 256 + (px + kx)) * 128;
        for (int cc = 0; cc < 8; ++cc) {
            __syncthreads();
            uint4 u = *(const uint4*)(g_feats + fb + cc * 16 + part * 8);
            int r0 = part * 8;
            At[(r0 + 0) * 68 + mL] = blo(u.x); At[(r0 + 1) * 68 + mL] = bhi(u.x);
            At[(r0 + 2) * 68 + mL] = blo(u.y); At[(r0 + 3) * 68 + mL] = bhi(u.y);
            At[(r0 + 4) * 68 + mL] = blo(u.z); At[(r0 + 5) * 68 + mL] = bhi(u.z);
            At[(r0 + 6) * 68 + mL] = blo(u.w); At[(r0 + 7) * 68 + mL] = bhi(u.w);
            __syncthreads();
            const float* wbase = g_W2 + (size_t)(pos * 128 + cc * 16) * 48 + oBase;
#pragma unroll 4
            for (int kk = 0; kk < 16; ++kk) {
                float a = At[kk * 68 + lane];
                const float* wr = wbase + kk * 48;
#pragma unroll
                for (int o = 0; o < 23; ++o)
                    acc[o] = fmaf(a, wr[o], acc[o]);
            }
        }
    }

    if (valid) {
#pragma unroll
        for (int o = 0; o < 23; ++o) {
            if (o < nO) {
                int oo = oBase + o;
                float vv = acc[o] + g_b2[oo];
                if (oo < 9) g_cls[(size_t)gm * 9 + oo] = f2b(vv);
                else        g_reg[(size_t)gm * 36 + (oo - 9)] = f2b(vv);
            }
        }
    }
}

// ---------------- gt-max: grid-stride over anchors, per-block per-k reduce, 16 atomics ----------------
__global__ __launch_bounds__(256) void k_gtmax(const float* __restrict__ gt) {
    __shared__ float red[4][KGT];
    int t = threadIdx.x;
    float m16[KGT];
#pragma unroll
    for (int k = 0; k < KGT; ++k) m16[k] = -1.0f;
    for (int n = blockIdx.x * 256 + t; n < NANCH; n += 256 * 256) {
        float v[KGT];
        anchor_ious(n, gt, v);
#pragma unroll
        for (int k = 0; k < KGT; ++k) m16[k] = fmaxf(m16[k], v[k]);
    }
#pragma unroll
    for (int k = 0; k < KGT; ++k) {
#pragma unroll
        for (int m = 32; m; m >>= 1) m16[k] = fmaxf(m16[k], __shfl_xor(m16[k], m, 64));
    }
    int lane = t & 63, wv = t >> 6;
    if (lane == 0) {
#pragma unroll
        for (int k = 0; k < KGT; ++k) red[wv][k] = m16[k];
    }
    __syncthreads();
    if (t < KGT) {
        float mx = fmaxf(fmaxf(red[0][t], red[1][t]), fmaxf(red[2][t], red[3][t]));
        unsigned u = __float_as_uint(mx);
        unsigned key = (u & 0x80000000u) ? ~u : (u | 0x80000000u);
        atomicMax(&g_keys[t], key);
    }
}

// ---------------- loss: recompute IoU (same noinline fn -> bit-exact), labels + BCE + smooth-L1 ----------------
__global__ __launch_bounds__(256) void k_loss(const float* __restrict__ gt) {
    __shared__ float red[4][4];
    int t = threadIdx.x;
    int n = blockIdx.x * 256 + t;
    float sb = 0.0f, ss = 0.0f, sx = 0.0f, sp = 0.0f;
    if (n < NANCH) {
        float v[KGT];
        anchor_ious(n, gt, v);
        bool inside = v[0] >= 0.0f;
        float maxi = -1.0f;
        bool best = false;
#pragma unroll
        for (int k = 0; k < KGT; ++k) {
            maxi = fmaxf(maxi, v[k]);
            unsigned e = g_keys[k];
            float gm = __uint_as_float((e & 0x80000000u) ? (e & 0x7FFFFFFFu) : ~e);
            best = best || (v[k] == gm);
        }
        bool ispos = inside && (best || (maxi >= 0.5f));
        if (inside) {
            float c = b2f(g_cls[n]);
            float z = ispos ? -c : c;
            sb = fmaxf(z, 0.0f) + log1pf(expf(-fabsf(z))); // softplus(z)
            ss = 1.0f;
        }
        if (ispos) {
            ushort4 rh = *(const ushort4*)(g_reg + (size_t)n * 4);
            float aa;
            aa = fabsf(b2f(rh.x)); sx += (aa < 1.0f) ? 0.5f * aa * aa : aa - 0.5f;
            aa = fabsf(b2f(rh.y)); sx += (aa < 1.0f) ? 0.5f * aa * aa : aa - 0.5f;
            aa = fabsf(b2f(rh.z)); sx += (aa < 1.0f) ? 0.5f * aa * aa : aa - 0.5f;
            aa = fabsf(b2f(rh.w)); sx += (aa < 1.0f) ? 0.5f * aa * aa : aa - 0.5f;
            sp = 1.0f;
        }
    }
#pragma unroll
    for (int m = 32; m; m >>= 1) {
        sb += __shfl_xor(sb, m, 64);
        ss += __shfl_xor(ss, m, 64);
        sx += __shfl_xor(sx, m, 64);
        sp += __shfl_xor(sp, m, 64);
    }
    int lane = t & 63, wv = t >> 6;
    if (lane == 0) { red[wv][0] = sb; red[wv][1] = ss; red[wv][2] = sx; red[wv][3] = sp; }
    __syncthreads();
    if (t < 4) {
        float s = red[0][t] + red[1][t] + red[2][t] + red[3][t];
        atomicAdd(&g_acc[t], s);
    }
}

// ---------------- finalize: dual-format store (bf16 exact in low16, like r2's proven store) ----------------
__global__ void k_fin(unsigned* out) {
    float res = g_acc[0] / g_acc[1] + g_acc[2] / g_acc[3];
    unsigned lo = (unsigned)f2b(res);
    unsigned hi = __float_as_uint(res) >> 16;
    out[0] = (hi << 16) | lo;
}

extern "C" void kernel_launch(void* const* d_in, const int* in_sizes, int n_in,
                              void* d_out, int out_size, void* d_ws, size_t ws_size,
                              hipStream_t stream) {
    (void)in_sizes; (void)n_in; (void)out_size; (void)d_ws; (void)ws_size;
    const float* image = (const float*)d_in[0];
    const float* gt    = (const float*)d_in[1];
    const float* Wb    = (const float*)d_in[2];
    const float* bb    = (const float*)d_in[3];
    const float* Wi    = (const float*)d_in[4];
    const float* bi    = (const float*)d_in[5];
    const float* Wc    = (const float*)d_in[6];
    const float* bc    = (const float*)d_in[7];
    const float* Wr    = (const float*)d_in[8];
    const float* br    = (const float*)d_in[9];

    k_init <<<1, 64, 0, stream>>>((unsigned*)d_out);
    k_conv1<<<8192, 256, 0, stream>>>(image, Wb, bb);
    k_w2   <<<217, 256, 0, stream>>>(Wi, bi, Wc, bc, Wr, br);
    k_convC<<<1009, 128, 0, stream>>>();
    k_gtmax<<<256, 256, 0, stream>>>(gt);
    k_loss <<<2269, 256, 0, stream>>>(gt);
    k_fin  <<<1, 1, 0, stream>>>((unsigned*)d_out);
}

// Round 8
// 334.878 us; speedup vs baseline: 1.6223x; 1.6223x over previous
//
#include <hip/hip_runtime.h>

// ---------------- problem constants ----------------
#define F2      254
#define NPIX    (F2 * F2)        // 64516 conv2 output pixels
#define NANCH   (NPIX * 9)       // 580644 anchors
#define KGT     16
#define GWC     (1.0f / 1024.0f) // gw == gh == 1/IMG

typedef __attribute__((ext_vector_type(8))) short bf16x8;
typedef __attribute__((ext_vector_type(4))) float f32x4;

// ---------------- static device storage ----------------
__device__ unsigned short g_feats[256 * 256 * 128];  // conv1 out, bf16, 16.78 MB
__device__ unsigned short g_cls[NPIX * 9];           // cls logits bf16
__device__ unsigned short g_reg[NPIX * 36];          // reg preds bf16
__device__ unsigned short g_W2s[36 * 3 * 64 * 8];    // combined weights, bf16, MFMA-B swizzled
__device__ float          g_b2[48];
__device__ float          g_acc[4];                  // bce_sum, sel_cnt, box_sum, pos_cnt
__device__ unsigned       g_keys[KGT];               // monotone-encoded gt-max

__device__ __forceinline__ float b2f(unsigned short h) {
    return __uint_as_float(((unsigned)h) << 16);
}
__device__ __forceinline__ unsigned short f2b(float f) {
    unsigned u = __float_as_uint(f);
    unsigned r = (u + 0x7FFFu + ((u >> 16) & 1u)) >> 16;
    return (unsigned short)r;
}

// ---------------- shared IoU core: ONE code instance -> bit-exact across passes ----------------
__device__ __attribute__((noinline)) void anchor_ious(int n, const float* __restrict__ gt,
                                                      float* __restrict__ v) {
    int w_idx = n / (F2 * 9);
    int rem = n - w_idx * (F2 * 9);
    int h_idx = rem / 9;
    int a = rem - h_idx * 9;
    int ri = a / 3, si = a - ri * 3;
    float rat = (ri == 0) ? 0.5f : (ri == 1) ? 1.0f : 2.0f;
    float scl = (si == 0) ? 0.2f : (si == 1) ? 0.4f : 0.7f;
    float rs = sqrtf(rat);
    float hw = scl * rs * 0.5f;
    float hh = scl / rs * 0.5f;
    float cx = (float)w_idx * (1.0f / 254.0f);
    float cy = (float)h_idx * (1.0f / 254.0f);
    float x1 = cx - hw, y1 = cy - hh, x2 = cx + hw, y2 = cy + hh;
    bool inside = (x1 >= 0.0f) && (y1 >= 0.0f) && (x2 < 1.0f) && (y2 < 1.0f);
    float s1 = (x2 - x1 + GWC) * (y2 - y1 + GWC);
    for (int k = 0; k < KGT; ++k) {
        float gx1 = gt[k * 4 + 0], gy1 = gt[k * 4 + 1];
        float gx2 = gt[k * 4 + 2], gy2 = gt[k * 4 + 3];
        float s2 = (gx2 - gx1 + GWC) * (gy2 - gy1 + GWC);
        float xa = fmaxf(x1, gx1), ya = fmaxf(y1, gy1);
        float xb = fminf(x2, gx2), yb = fminf(y2, gy2);
        float iw = fmaxf(xb - xa + GWC, 0.0f);
        float ih = fmaxf(yb - ya + GWC, 0.0f);
        float inter = iw * ih;
        float iou = inter / (s1 + s2 - inter);
        v[k] = inside ? iou : -1.0f;
    }
}

// ---------------- init ----------------
__global__ void k_init(unsigned* out) {
    int t = threadIdx.x;
    if (t < 4) g_acc[t] = 0.0f;
    if (t >= 4 && t < 4 + KGT) g_keys[t - 4] = 0x407FFFFFu; // enc(-1.0f)
    if (t == 32) out[0] = 0x3F803F80u;
}

// ---------------- conv1: 1024x1024x3 (fp32) -> 256x256x128 bf16, 4x4 stride 4 ----------------
__global__ __launch_bounds__(256) void k_conv1(const float* __restrict__ img,
                                               const float* __restrict__ Wb,
                                               const float* __restrict__ bb) {
    int t = threadIdx.x;
    int g = t & 31;   // oc group -> oc = 4g..4g+3
    int mi = t >> 5;  // pixel within block
    int p = blockIdx.x * 8 + mi;
    int oy = p >> 8, ox = p & 255;
    const float* ib = img + ((size_t)oy * 4 * 1024 + (size_t)ox * 4) * 3;
    float4 acc = *(const float4*)(bb + g * 4);
#pragma unroll
    for (int r = 0; r < 4; ++r) {
#pragma unroll
        for (int q = 0; q < 3; ++q) {
            float4 pf = *(const float4*)(ib + (size_t)r * 3072 + q * 4);
            float pv[4] = {pf.x, pf.y, pf.z, pf.w};
#pragma unroll
            for (int e = 0; e < 4; ++e) {
                float4 wv4 = *(const float4*)(Wb + (size_t)((r * 3 + q) * 4 + e) * 128 + g * 4);
                acc.x = fmaf(pv[e], wv4.x, acc.x);
                acc.y = fmaf(pv[e], wv4.y, acc.y);
                acc.z = fmaf(pv[e], wv4.z, acc.z);
                acc.w = fmaf(pv[e], wv4.w, acc.w);
            }
        }
    }
    ushort4 o;
    o.x = f2b(acc.x); o.y = f2b(acc.y); o.z = f2b(acc.z); o.w = f2b(acc.w);
    *(ushort4*)(g_feats + (size_t)p * 128 + g * 4) = o;
}

// ---------------- W2 precombine -> bf16, MFMA-B swizzled: g_W2s[((kt*3+nt)*64+l)*8+j] ----------------
// element (kt,nt,l,j): k = kt*32 + (l>>4)*8 + j, o = nt*16 + (l&15); W2[k][o] = sum_oc Wi[k][oc]*Wcr[oc][o]
__global__ __launch_bounds__(256) void k_w2(const float* __restrict__ Wi,
                                            const float* __restrict__ bi,
                                            const float* __restrict__ Wc,
                                            const float* __restrict__ bc,
                                            const float* __restrict__ Wr,
                                            const float* __restrict__ br) {
    int tid = blockIdx.x * 256 + threadIdx.x;
    if (tid < 55296) {
        int j = tid & 7;
        int l = (tid >> 3) & 63;
        int rest = tid >> 9;          // kt*3 + nt
        int nt = rest % 3;
        int kt = rest / 3;
        int k = kt * 32 + (l >> 4) * 8 + j;
        int o = nt * 16 + (l & 15);
        float acc = 0.0f;
        if (o < 45) {
            const float* wik = Wi + (size_t)k * 256;
            if (o < 9) {
                const float* wcp = Wc + o;
#pragma unroll 4
                for (int oc = 0; oc < 256; ++oc) acc = fmaf(wik[oc], wcp[oc * 9], acc);
            } else {
                const float* wrp = Wr + (o - 9);
#pragma unroll 4
                for (int oc = 0; oc < 256; ++oc) acc = fmaf(wik[oc], wrp[oc * 36], acc);
            }
        }
        g_W2s[tid] = f2b(acc);
    } else if (tid < 55296 + 48) {
        int o = tid - 55296;
        float acc = 0.0f;
        if (o < 45) {
            acc = (o < 9) ? bc[o] : br[o - 9];
            for (int oc = 0; oc < 256; ++oc) {
                float wc = (o < 9) ? Wc[oc * 9 + o] : Wr[oc * 36 + (o - 9)];
                acc = fmaf(bi[oc], wc, acc);
            }
        }
        g_b2[o] = acc;
    }
}

// ---------------- combined conv via MFMA: feats -> cls (NPIX x 9), reg (NPIX x 36) ----------------
// GEMM M=NPIX, K=1152, N=45(pad 48). Wave = 16-pixel M-tile x 48 outputs; 3 acc frags; no LDS, no barriers.
// A-frag: lane m=l&15, k=quad*8+j -> 8 contiguous bf16 from g_feats. B-frag: pre-swizzled g_W2s.
// C/D: col=l&15, row=quad*4+reg.
__global__ __launch_bounds__(256) void k_convC() {
    int t = threadIdx.x;
    int l = t & 63;
    int quad = l >> 4;
    int tile = blockIdx.x * 4 + (t >> 6);
    int m0 = tile * 16;
    int mA = min(m0 + (l & 15), NPIX - 1);
    int py = mA / F2, px = mA - py * F2;

    f32x4 acc0 = {0.0f, 0.0f, 0.0f, 0.0f};
    f32x4 acc1 = {0.0f, 0.0f, 0.0f, 0.0f};
    f32x4 acc2 = {0.0f, 0.0f, 0.0f, 0.0f};

    int kt = 0;
#pragma unroll
    for (int ky = 0; ky < 3; ++ky) {
#pragma unroll
        for (int kx = 0; kx < 3; ++kx) {
            const unsigned short* ap =
                g_feats + ((size_t)(py + ky) * 256 + (px + kx)) * 128 + quad * 8;
#pragma unroll
            for (int kc = 0; kc < 4; ++kc) {
                bf16x8 a = *(const bf16x8*)(ap + kc * 32);
                const unsigned short* bp = g_W2s + (size_t)kt * 1536 + l * 8;
                bf16x8 b0 = *(const bf16x8*)(bp);
                bf16x8 b1 = *(const bf16x8*)(bp + 512);
                bf16x8 b2v = *(const bf16x8*)(bp + 1024);
                acc0 = __builtin_amdgcn_mfma_f32_16x16x32_bf16(a, b0, acc0, 0, 0, 0);
                acc1 = __builtin_amdgcn_mfma_f32_16x16x32_bf16(a, b1, acc1, 0, 0, 0);
                acc2 = __builtin_amdgcn_mfma_f32_16x16x32_bf16(a, b2v, acc2, 0, 0, 0);
                ++kt;
            }
        }
    }

    int n0 = l & 15;
    int mB = m0 + quad * 4;
#pragma unroll
    for (int nt = 0; nt < 3; ++nt) {
        int n = nt * 16 + n0;
        if (n >= 45) continue;
        float bias = g_b2[n];
        f32x4 av = (nt == 0) ? acc0 : (nt == 1) ? acc1 : acc2;
#pragma unroll
        for (int r = 0; r < 4; ++r) {
            int m = mB + r;
            if (m < NPIX) {
                float vv = av[r] + bias;
                if (n < 9) g_cls[(size_t)m * 9 + n] = f2b(vv);
                else       g_reg[(size_t)m * 36 + (n - 9)] = f2b(vv);
            }
        }
    }
}

// ---------------- gt-max: grid-stride over anchors, per-block per-k reduce, 16 atomics ----------------
__global__ __launch_bounds__(256) void k_gtmax(const float* __restrict__ gt) {
    __shared__ float red[4][KGT];
    int t = threadIdx.x;
    float m16[KGT];
#pragma unroll
    for (int k = 0; k < KGT; ++k) m16[k] = -1.0f;
    for (int n = blockIdx.x * 256 + t; n < NANCH; n += 256 * 256) {
        float v[KGT];
        anchor_ious(n, gt, v);
#pragma unroll
        for (int k = 0; k < KGT; ++k) m16[k] = fmaxf(m16[k], v[k]);
    }
#pragma unroll
    for (int k = 0; k < KGT; ++k) {
#pragma unroll
        for (int m = 32; m; m >>= 1) m16[k] = fmaxf(m16[k], __shfl_xor(m16[k], m, 64));
    }
    int lane = t & 63, wv = t >> 6;
    if (lane == 0) {
#pragma unroll
        for (int k = 0; k < KGT; ++k) red[wv][k] = m16[k];
    }
    __syncthreads();
    if (t < KGT) {
        float mx = fmaxf(fmaxf(red[0][t], red[1][t]), fmaxf(red[2][t], red[3][t]));
        unsigned u = __float_as_uint(mx);
        unsigned key = (u & 0x80000000u) ? ~u : (u | 0x80000000u);
        atomicMax(&g_keys[t], key);
    }
}

// ---------------- loss: recompute IoU (same noinline fn -> bit-exact), labels + BCE + smooth-L1 ----------------
__global__ __launch_bounds__(256) void k_loss(const float* __restrict__ gt) {
    __shared__ float red[4][4];
    int t = threadIdx.x;
    int n = blockIdx.x * 256 + t;
    float sb = 0.0f, ss = 0.0f, sx = 0.0f, sp = 0.0f;
    if (n < NANCH) {
        float v[KGT];
        anchor_ious(n, gt, v);
        bool inside = v[0] >= 0.0f;
        float maxi = -1.0f;
        bool best = false;
#pragma unroll
        for (int k = 0; k < KGT; ++k) {
            maxi = fmaxf(maxi, v[k]);
            unsigned e = g_keys[k];
            float gm = __uint_as_float((e & 0x80000000u) ? (e & 0x7FFFFFFFu) : ~e);
            best = best || (v[k] == gm);
        }
        bool ispos = inside && (best || (maxi >= 0.5f));
        if (inside) {
            float c = b2f(g_cls[n]);
            float z = ispos ? -c : c;
            sb = fmaxf(z, 0.0f) + log1pf(expf(-fabsf(z))); // softplus(z)
            ss = 1.0f;
        }
        if (ispos) {
            ushort4 rh = *(const ushort4*)(g_reg + (size_t)n * 4);
            float aa;
            aa = fabsf(b2f(rh.x)); sx += (aa < 1.0f) ? 0.5f * aa * aa : aa - 0.5f;
            aa = fabsf(b2f(rh.y)); sx += (aa < 1.0f) ? 0.5f * aa * aa : aa - 0.5f;
            aa = fabsf(b2f(rh.z)); sx += (aa < 1.0f) ? 0.5f * aa * aa : aa - 0.5f;
            aa = fabsf(b2f(rh.w)); sx += (aa < 1.0f) ? 0.5f * aa * aa : aa - 0.5f;
            sp = 1.0f;
        }
    }
#pragma unroll
    for (int m = 32; m; m >>= 1) {
        sb += __shfl_xor(sb, m, 64);
        ss += __shfl_xor(ss, m, 64);
        sx += __shfl_xor(sx, m, 64);
        sp += __shfl_xor(sp, m, 64);
    }
    int lane = t & 63, wv = t >> 6;
    if (lane == 0) { red[wv][0] = sb; red[wv][1] = ss; red[wv][2] = sx; red[wv][3] = sp; }
    __syncthreads();
    if (t < 4) {
        float s = red[0][t] + red[1][t] + red[2][t] + red[3][t];
        atomicAdd(&g_acc[t], s);
    }
}

// ---------------- finalize: dual-format store (bf16 exact in low16) ----------------
__global__ void k_fin(unsigned* out) {
    float res = g_acc[0] / g_acc[1] + g_acc[2] / g_acc[3];
    unsigned lo = (unsigned)f2b(res);
    unsigned hi = __float_as_uint(res) >> 16;
    out[0] = (hi << 16) | lo;
}

extern "C" void kernel_launch(void* const* d_in, const int* in_sizes, int n_in,
                              void* d_out, int out_size, void* d_ws, size_t ws_size,
                              hipStream_t stream) {
    (void)in_sizes; (void)n_in; (void)out_size; (void)d_ws; (void)ws_size;
    const float* image = (const float*)d_in[0];
    const float* gt    = (const float*)d_in[1];
    const float* Wb    = (const float*)d_in[2];
    const float* bb    = (const float*)d_in[3];
    const float* Wi    = (const float*)d_in[4];
    const float* bi    = (const float*)d_in[5];
    const float* Wc    = (const float*)d_in[6];
    const float* bc    = (const float*)d_in[7];
    const float* Wr    = (const float*)d_in[8];
    const float* br    = (const float*)d_in[9];

    k_init <<<1, 64, 0, stream>>>((unsigned*)d_out);
    k_conv1<<<8192, 256, 0, stream>>>(image, Wb, bb);
    k_w2   <<<217, 256, 0, stream>>>(Wi, bi, Wc, bc, Wr, br);
    k_convC<<<1009, 256, 0, stream>>>();
    k_gtmax<<<256, 256, 0, stream>>>(gt);
    k_loss <<<2269, 256, 0, stream>>>(gt);
    k_fin  <<<1, 1, 0, stream>>>((unsigned*)d_out);
}

// Round 9
// 241.864 us; speedup vs baseline: 2.2462x; 1.3846x over previous
//
#include <hip/hip_runtime.h>

// ---------------- problem constants ----------------
#define F2      254
#define NPIX    (F2 * F2)        // 64516 conv2 output pixels
#define NANCH   (NPIX * 9)       // 580644 anchors
#define KGT     16
#define GWC     (1.0f / 1024.0f) // gw == gh == 1/IMG

typedef __attribute__((ext_vector_type(8))) short bf16x8;
typedef __attribute__((ext_vector_type(4))) float f32x4;

// ---------------- static device storage ----------------
__device__ unsigned short g_feats[256 * 256 * 128];  // conv1 out, bf16, 16.78 MB
__device__ unsigned short g_cls[NPIX * 9];           // cls logits bf16
__device__ unsigned short g_reg[NPIX * 36];          // reg preds bf16
__device__ unsigned short g_W2s[36 * 3 * 64 * 8];    // combined weights, bf16, MFMA-B swizzled
__device__ float          g_b2[48];
__device__ float          g_acc[4];                  // bce_sum, sel_cnt, box_sum, pos_cnt
__device__ unsigned       g_keys[KGT];               // monotone-encoded gt-max

__device__ __forceinline__ float b2f(unsigned short h) {
    return __uint_as_float(((unsigned)h) << 16);
}
__device__ __forceinline__ unsigned short f2b(float f) {
    unsigned u = __float_as_uint(f);
    unsigned r = (u + 0x7FFFu + ((u >> 16) & 1u)) >> 16;
    return (unsigned short)r;
}

// ---------------- IoU core, fully inlined + unrolled: v[] stays in VGPRs ----------------
// Bit-exact across callers: all ops are deterministic FP instructions; no contractible
// a*b+c patterns exist in this expression tree (products and sums are disjoint).
__device__ __forceinline__ bool anchor_ious(int n, const float* __restrict__ gt,
                                            float* __restrict__ v) {
    int w_idx = n / (F2 * 9);
    int rem = n - w_idx * (F2 * 9);
    int h_idx = rem / 9;
    int a = rem - h_idx * 9;
    int ri = a / 3, si = a - ri * 3;
    float rat = (ri == 0) ? 0.5f : (ri == 1) ? 1.0f : 2.0f;
    float scl = (si == 0) ? 0.2f : (si == 1) ? 0.4f : 0.7f;
    float rs = sqrtf(rat);
    float hw = scl * rs * 0.5f;
    float hh = scl / rs * 0.5f;
    float cx = (float)w_idx * (1.0f / 254.0f);
    float cy = (float)h_idx * (1.0f / 254.0f);
    float x1 = cx - hw, y1 = cy - hh, x2 = cx + hw, y2 = cy + hh;
    bool inside = (x1 >= 0.0f) && (y1 >= 0.0f) && (x2 < 1.0f) && (y2 < 1.0f);
    if (!inside) return false;
    float s1 = (x2 - x1 + GWC) * (y2 - y1 + GWC);
#pragma unroll
    for (int k = 0; k < KGT; ++k) {
        float gx1 = gt[k * 4 + 0], gy1 = gt[k * 4 + 1];
        float gx2 = gt[k * 4 + 2], gy2 = gt[k * 4 + 3];
        float s2 = (gx2 - gx1 + GWC) * (gy2 - gy1 + GWC);
        float xa = fmaxf(x1, gx1), ya = fmaxf(y1, gy1);
        float xb = fminf(x2, gx2), yb = fminf(y2, gy2);
        float iw = fmaxf(xb - xa + GWC, 0.0f);
        float ih = fmaxf(yb - ya + GWC, 0.0f);
        float inter = iw * ih;
        v[k] = inter / (s1 + s2 - inter);
    }
    return true;
}

// ---------------- init ----------------
__global__ void k_init(unsigned* out) {
    int t = threadIdx.x;
    if (t < 4) g_acc[t] = 0.0f;
    if (t >= 4 && t < 4 + KGT) g_keys[t - 4] = 0x407FFFFFu; // enc(-1.0f)
    if (t == 32) out[0] = 0x3F803F80u;
}

// ---------------- conv1: 1024x1024x3 (fp32) -> 256x256x128 bf16, 4x4 stride 4 ----------------
__global__ __launch_bounds__(256) void k_conv1(const float* __restrict__ img,
                                               const float* __restrict__ Wb,
                                               const float* __restrict__ bb) {
    int t = threadIdx.x;
    int g = t & 31;   // oc group -> oc = 4g..4g+3
    int mi = t >> 5;  // pixel within block
    int p = blockIdx.x * 8 + mi;
    int oy = p >> 8, ox = p & 255;
    const float* ib = img + ((size_t)oy * 4 * 1024 + (size_t)ox * 4) * 3;
    float4 acc = *(const float4*)(bb + g * 4);
#pragma unroll
    for (int r = 0; r < 4; ++r) {
#pragma unroll
        for (int q = 0; q < 3; ++q) {
            float4 pf = *(const float4*)(ib + (size_t)r * 3072 + q * 4);
            float pv[4] = {pf.x, pf.y, pf.z, pf.w};
#pragma unroll
            for (int e = 0; e < 4; ++e) {
                float4 wv4 = *(const float4*)(Wb + (size_t)((r * 3 + q) * 4 + e) * 128 + g * 4);
                acc.x = fmaf(pv[e], wv4.x, acc.x);
                acc.y = fmaf(pv[e], wv4.y, acc.y);
                acc.z = fmaf(pv[e], wv4.z, acc.z);
                acc.w = fmaf(pv[e], wv4.w, acc.w);
            }
        }
    }
    ushort4 o;
    o.x = f2b(acc.x); o.y = f2b(acc.y); o.z = f2b(acc.z); o.w = f2b(acc.w);
    *(ushort4*)(g_feats + (size_t)p * 128 + g * 4) = o;
}

// ---------------- W2 precombine -> bf16, MFMA-B swizzled: g_W2s[((kt*3+nt)*64+l)*8+j] ----------------
__global__ __launch_bounds__(256) void k_w2(const float* __restrict__ Wi,
                                            const float* __restrict__ bi,
                                            const float* __restrict__ Wc,
                                            const float* __restrict__ bc,
                                            const float* __restrict__ Wr,
                                            const float* __restrict__ br) {
    int tid = blockIdx.x * 256 + threadIdx.x;
    if (tid < 55296) {
        int j = tid & 7;
        int l = (tid >> 3) & 63;
        int rest = tid >> 9;          // kt*3 + nt
        int nt = rest % 3;
        int kt = rest / 3;
        int k = kt * 32 + (l >> 4) * 8 + j;
        int o = nt * 16 + (l & 15);
        float acc = 0.0f;
        if (o < 45) {
            const float* wik = Wi + (size_t)k * 256;
            if (o < 9) {
                const float* wcp = Wc + o;
#pragma unroll 4
                for (int oc = 0; oc < 256; ++oc) acc = fmaf(wik[oc], wcp[oc * 9], acc);
            } else {
                const float* wrp = Wr + (o - 9);
#pragma unroll 4
                for (int oc = 0; oc < 256; ++oc) acc = fmaf(wik[oc], wrp[oc * 36], acc);
            }
        }
        g_W2s[tid] = f2b(acc);
    } else if (tid < 55296 + 48) {
        int o = tid - 55296;
        float acc = 0.0f;
        if (o < 45) {
            acc = (o < 9) ? bc[o] : br[o - 9];
            for (int oc = 0; oc < 256; ++oc) {
                float wc = (o < 9) ? Wc[oc * 9 + o] : Wr[oc * 36 + (o - 9)];
                acc = fmaf(bi[oc], wc, acc);
            }
        }
        g_b2[o] = acc;
    }
}

// ---------------- combined conv via MFMA: feats -> cls (NPIX x 9), reg (NPIX x 36) ----------------
__global__ __launch_bounds__(256) void k_convC() {
    int t = threadIdx.x;
    int l = t & 63;
    int quad = l >> 4;
    int tile = blockIdx.x * 4 + (t >> 6);
    int m0 = tile * 16;
    int mA = min(m0 + (l & 15), NPIX - 1);
    int py = mA / F2, px = mA - py * F2;

    f32x4 acc0 = {0.0f, 0.0f, 0.0f, 0.0f};
    f32x4 acc1 = {0.0f, 0.0f, 0.0f, 0.0f};
    f32x4 acc2 = {0.0f, 0.0f, 0.0f, 0.0f};

    int kt = 0;
#pragma unroll
    for (int ky = 0; ky < 3; ++ky) {
#pragma unroll
        for (int kx = 0; kx < 3; ++kx) {
            const unsigned short* ap =
                g_feats + ((size_t)(py + ky) * 256 + (px + kx)) * 128 + quad * 8;
#pragma unroll
            for (int kc = 0; kc < 4; ++kc) {
                bf16x8 a = *(const bf16x8*)(ap + kc * 32);
                const unsigned short* bp = g_W2s + (size_t)kt * 1536 + l * 8;
                bf16x8 b0 = *(const bf16x8*)(bp);
                bf16x8 b1 = *(const bf16x8*)(bp + 512);
                bf16x8 b2v = *(const bf16x8*)(bp + 1024);
                acc0 = __builtin_amdgcn_mfma_f32_16x16x32_bf16(a, b0, acc0, 0, 0, 0);
                acc1 = __builtin_amdgcn_mfma_f32_16x16x32_bf16(a, b1, acc1, 0, 0, 0);
                acc2 = __builtin_amdgcn_mfma_f32_16x16x32_bf16(a, b2v, acc2, 0, 0, 0);
                ++kt;
            }
        }
    }

    int n0 = l & 15;
    int mB = m0 + quad * 4;
#pragma unroll
    for (int nt = 0; nt < 3; ++nt) {
        int n = nt * 16 + n0;
        if (n >= 45) continue;
        float bias = g_b2[n];
        f32x4 av = (nt == 0) ? acc0 : (nt == 1) ? acc1 : acc2;
#pragma unroll
        for (int r = 0; r < 4; ++r) {
            int m = mB + r;
            if (m < NPIX) {
                float vv = av[r] + bias;
                if (n < 9) g_cls[(size_t)m * 9 + n] = f2b(vv);
                else       g_reg[(size_t)m * 36 + (n - 9)] = f2b(vv);
            }
        }
    }
}

// ---------------- gt-max: early-out on outside, registers only, 16 atomics/block ----------------
__global__ __launch_bounds__(256) void k_gtmax(const float* __restrict__ gt) {
    __shared__ float red[4][KGT];
    int t = threadIdx.x;
    float m16[KGT];
#pragma unroll
    for (int k = 0; k < KGT; ++k) m16[k] = -1.0f;
    for (int n = blockIdx.x * 256 + t; n < NANCH; n += 256 * 256) {
        float v[KGT];
        if (anchor_ious(n, gt, v)) {
#pragma unroll
            for (int k = 0; k < KGT; ++k) m16[k] = fmaxf(m16[k], v[k]);
        }
    }
#pragma unroll
    for (int k = 0; k < KGT; ++k) {
#pragma unroll
        for (int m = 32; m; m >>= 1) m16[k] = fmaxf(m16[k], __shfl_xor(m16[k], m, 64));
    }
    int lane = t & 63, wv = t >> 6;
    if (lane == 0) {
#pragma unroll
        for (int k = 0; k < KGT; ++k) red[wv][k] = m16[k];
    }
    __syncthreads();
    if (t < KGT) {
        float mx = fmaxf(fmaxf(red[0][t], red[1][t]), fmaxf(red[2][t], red[3][t]));
        unsigned u = __float_as_uint(mx);
        unsigned key = (u & 0x80000000u) ? ~u : (u | 0x80000000u);
        atomicMax(&g_keys[t], key);
    }
}

// ---------------- loss: early-out on outside, registers only ----------------
__global__ __launch_bounds__(256) void k_loss(const float* __restrict__ gt) {
    __shared__ float red[4][4];
    int t = threadIdx.x;
    int n = blockIdx.x * 256 + t;
    float sb = 0.0f, ss = 0.0f, sx = 0.0f, sp = 0.0f;
    if (n < NANCH) {
        float v[KGT];
        bool inside = anchor_ious(n, gt, v);
        if (inside) {
            float maxi = -1.0f;
            bool best = false;
#pragma unroll
            for (int k = 0; k < KGT; ++k) {
                maxi = fmaxf(maxi, v[k]);
                unsigned e = g_keys[k];
                float gm = __uint_as_float((e & 0x80000000u) ? (e & 0x7FFFFFFFu) : ~e);
                best = best || (v[k] == gm);
            }
            bool ispos = best || (maxi >= 0.5f);
            float c = b2f(g_cls[n]);
            float z = ispos ? -c : c;
            sb = fmaxf(z, 0.0f) + log1pf(expf(-fabsf(z))); // softplus(z)
            ss = 1.0f;
            if (ispos) {
                ushort4 rh = *(const ushort4*)(g_reg + (size_t)n * 4);
                float aa;
                aa = fabsf(b2f(rh.x)); sx += (aa < 1.0f) ? 0.5f * aa * aa : aa - 0.5f;
                aa = fabsf(b2f(rh.y)); sx += (aa < 1.0f) ? 0.5f * aa * aa : aa - 0.5f;
                aa = fabsf(b2f(rh.z)); sx += (aa < 1.0f) ? 0.5f * aa * aa : aa - 0.5f;
                aa = fabsf(b2f(rh.w)); sx += (aa < 1.0f) ? 0.5f * aa * aa : aa - 0.5f;
                sp = 1.0f;
            }
        }
    }
#pragma unroll
    for (int m = 32; m; m >>= 1) {
        sb += __shfl_xor(sb, m, 64);
        ss += __shfl_xor(ss, m, 64);
        sx += __shfl_xor(sx, m, 64);
        sp += __shfl_xor(sp, m, 64);
    }
    int lane = t & 63, wv = t >> 6;
    if (lane == 0) { red[wv][0] = sb; red[wv][1] = ss; red[wv][2] = sx; red[wv][3] = sp; }
    __syncthreads();
    if (t < 4) {
        float s = red[0][t] + red[1][t] + red[2][t] + red[3][t];
        atomicAdd(&g_acc[t], s);
    }
}

// ---------------- finalize: dual-format store (bf16 exact in low16) ----------------
__global__ void k_fin(unsigned* out) {
    float res = g_acc[0] / g_acc[1] + g_acc[2] / g_acc[3];
    unsigned lo = (unsigned)f2b(res);
    unsigned hi = __float_as_uint(res) >> 16;
    out[0] = (hi << 16) | lo;
}

extern "C" void kernel_launch(void* const* d_in, const int* in_sizes, int n_in,
                              void* d_out, int out_size, void* d_ws, size_t ws_size,
                              hipStream_t stream) {
    (void)in_sizes; (void)n_in; (void)out_size; (void)d_ws; (void)ws_size;
    const float* image = (const float*)d_in[0];
    const float* gt    = (const float*)d_in[1];
    const float* Wb    = (const float*)d_in[2];
    const float* bb    = (const float*)d_in[3];
    const float* Wi    = (const float*)d_in[4];
    const float* bi    = (const float*)d_in[5];
    const float* Wc    = (const float*)d_in[6];
    const float* bc    = (const float*)d_in[7];
    const float* Wr    = (const float*)d_in[8];
    const float* br    = (const float*)d_in[9];

    k_init <<<1, 64, 0, stream>>>((unsigned*)d_out);
    k_conv1<<<8192, 256, 0, stream>>>(image, Wb, bb);
    k_w2   <<<217, 256, 0, stream>>>(Wi, bi, Wc, bc, Wr, br);
    k_convC<<<1009, 256, 0, stream>>>();
    k_gtmax<<<256, 256, 0, stream>>>(gt);
    k_loss <<<2269, 256, 0, stream>>>(gt);
    k_fin  <<<1, 1, 0, stream>>>((unsigned*)d_out);
}

// Round 10
// 202.636 us; speedup vs baseline: 2.6810x; 1.1936x over previous
//
#include <hip/hip_runtime.h>

// ---------------- problem constants ----------------
#define F2      254
#define NPIX    (F2 * F2)        // 64516 conv2 output pixels
#define NANCH   (NPIX * 9)       // 580644 anchors
#define KGT     16
#define GWC     (1.0f / 1024.0f) // gw == gh == 1/IMG

typedef __attribute__((ext_vector_type(8))) short bf16x8;
typedef __attribute__((ext_vector_type(4))) float f32x4;

// ---------------- static device storage ----------------
__device__ unsigned short g_feats[256 * 256 * 128];  // conv1 out, bf16, 16.78 MB
__device__ unsigned short g_cls[NPIX * 9];           // cls logits bf16
__device__ unsigned short g_reg[NPIX * 36];          // reg preds bf16
__device__ unsigned short g_W2s[36 * 3 * 64 * 8];    // combined weights, bf16, MFMA-B swizzled
__device__ float          g_b2[48];
__device__ float          g_acc[4];                  // bce_sum, sel_cnt, box_sum, pos_cnt
__device__ unsigned       g_keys[KGT];               // monotone-encoded gt-max

__device__ __forceinline__ float b2f(unsigned short h) {
    return __uint_as_float(((unsigned)h) << 16);
}
__device__ __forceinline__ unsigned short f2b(float f) {
    unsigned u = __float_as_uint(f);
    unsigned r = (u + 0x7FFFu + ((u >> 16) & 1u)) >> 16;
    return (unsigned short)r;
}

// ---------------- IoU core, fully inlined + unrolled: v[] stays in VGPRs ----------------
__device__ __forceinline__ bool anchor_ious(int n, const float* __restrict__ gt,
                                            float* __restrict__ v) {
    int w_idx = n / (F2 * 9);
    int rem = n - w_idx * (F2 * 9);
    int h_idx = rem / 9;
    int a = rem - h_idx * 9;
    int ri = a / 3, si = a - ri * 3;
    float rat = (ri == 0) ? 0.5f : (ri == 1) ? 1.0f : 2.0f;
    float scl = (si == 0) ? 0.2f : (si == 1) ? 0.4f : 0.7f;
    float rs = sqrtf(rat);
    float hw = scl * rs * 0.5f;
    float hh = scl / rs * 0.5f;
    float cx = (float)w_idx * (1.0f / 254.0f);
    float cy = (float)h_idx * (1.0f / 254.0f);
    float x1 = cx - hw, y1 = cy - hh, x2 = cx + hw, y2 = cy + hh;
    bool inside = (x1 >= 0.0f) && (y1 >= 0.0f) && (x2 < 1.0f) && (y2 < 1.0f);
    if (!inside) return false;
    float s1 = (x2 - x1 + GWC) * (y2 - y1 + GWC);
#pragma unroll
    for (int k = 0; k < KGT; ++k) {
        float gx1 = gt[k * 4 + 0], gy1 = gt[k * 4 + 1];
        float gx2 = gt[k * 4 + 2], gy2 = gt[k * 4 + 3];
        float s2 = (gx2 - gx1 + GWC) * (gy2 - gy1 + GWC);
        float xa = fmaxf(x1, gx1), ya = fmaxf(y1, gy1);
        float xb = fminf(x2, gx2), yb = fminf(y2, gy2);
        float iw = fmaxf(xb - xa + GWC, 0.0f);
        float ih = fmaxf(yb - ya + GWC, 0.0f);
        float inter = iw * ih;
        v[k] = inter / (s1 + s2 - inter);
    }
    return true;
}

// ---------------- init ----------------
__global__ void k_init(unsigned* out) {
    int t = threadIdx.x;
    if (t < 4) g_acc[t] = 0.0f;
    if (t >= 4 && t < 4 + KGT) g_keys[t - 4] = 0x407FFFFFu; // enc(-1.0f)
    if (t == 32) out[0] = 0x3F803F80u;
}

// ---------------- conv1 v2: wave = 64 pixels x 32 oc; weights via wave-uniform SCALAR loads ----------------
// Wb addresses are SGPR-derived (readfirstlane'd wave id) -> s_load_dwordx4 through K$,
// vector path carries only the 12 pixel float4 loads per lane. Same fp32 FMA order as before.
__global__ __launch_bounds__(256) void k_conv1(const float* __restrict__ img,
                                               const float* __restrict__ Wb,
                                               const float* __restrict__ bb) {
    int t = threadIdx.x;
    int lane = t & 63;
    int wave = __builtin_amdgcn_readfirstlane(t >> 6);
    int ocb = wave * 32;                         // 32 output channels per wave
    int p = blockIdx.x * 64 + lane;              // output pixel
    int oy = p >> 8, ox = p & 255;
    const float* ib = img + ((size_t)oy * 4 * 1024 + (size_t)ox * 4) * 3;

    float4 acc[8];
#pragma unroll
    for (int j = 0; j < 8; ++j) acc[j] = *(const float4*)(bb + ocb + j * 4);

#pragma unroll
    for (int r = 0; r < 4; ++r) {
        float4 p0 = *(const float4*)(ib + (size_t)r * 3072);
        float4 p1 = *(const float4*)(ib + (size_t)r * 3072 + 4);
        float4 p2 = *(const float4*)(ib + (size_t)r * 3072 + 8);
        float px[12] = {p0.x, p0.y, p0.z, p0.w, p1.x, p1.y, p1.z, p1.w, p2.x, p2.y, p2.z, p2.w};
#pragma unroll
        for (int q = 0; q < 12; ++q) {
            const float* wr = Wb + (size_t)(r * 12 + q) * 128 + ocb;  // wave-uniform -> s_load
#pragma unroll
            for (int j = 0; j < 8; ++j) {
                float4 w = *(const float4*)(wr + j * 4);
                acc[j].x = fmaf(px[q], w.x, acc[j].x);
                acc[j].y = fmaf(px[q], w.y, acc[j].y);
                acc[j].z = fmaf(px[q], w.z, acc[j].z);
                acc[j].w = fmaf(px[q], w.w, acc[j].w);
            }
        }
    }
#pragma unroll
    for (int j = 0; j < 8; ++j) {
        ushort4 o;
        o.x = f2b(acc[j].x); o.y = f2b(acc[j].y); o.z = f2b(acc[j].z); o.w = f2b(acc[j].w);
        *(ushort4*)(g_feats + (size_t)p * 128 + ocb + j * 4) = o;
    }
}

// ---------------- W2 precombine -> bf16, MFMA-B swizzled: g_W2s[((kt*3+nt)*64+l)*8+j] ----------------
__global__ __launch_bounds__(256) void k_w2(const float* __restrict__ Wi,
                                            const float* __restrict__ bi,
                                            const float* __restrict__ Wc,
                                            const float* __restrict__ bc,
                                            const float* __restrict__ Wr,
                                            const float* __restrict__ br) {
    int tid = blockIdx.x * 256 + threadIdx.x;
    if (tid < 55296) {
        int j = tid & 7;
        int l = (tid >> 3) & 63;
        int rest = tid >> 9;          // kt*3 + nt
        int nt = rest % 3;
        int kt = rest / 3;
        int k = kt * 32 + (l >> 4) * 8 + j;
        int o = nt * 16 + (l & 15);
        float acc = 0.0f;
        if (o < 45) {
            const float* wik = Wi + (size_t)k * 256;
            if (o < 9) {
                const float* wcp = Wc + o;
#pragma unroll 4
                for (int oc = 0; oc < 256; ++oc) acc = fmaf(wik[oc], wcp[oc * 9], acc);
            } else {
                const float* wrp = Wr + (o - 9);
#pragma unroll 4
                for (int oc = 0; oc < 256; ++oc) acc = fmaf(wik[oc], wrp[oc * 36], acc);
            }
        }
        g_W2s[tid] = f2b(acc);
    } else if (tid < 55296 + 48) {
        int o = tid - 55296;
        float acc = 0.0f;
        if (o < 45) {
            acc = (o < 9) ? bc[o] : br[o - 9];
            for (int oc = 0; oc < 256; ++oc) {
                float wc = (o < 9) ? Wc[oc * 9 + o] : Wr[oc * 36 + (o - 9)];
                acc = fmaf(bi[oc], wc, acc);
            }
        }
        g_b2[o] = acc;
    }
}

// ---------------- combined conv via MFMA: feats -> cls (NPIX x 9), reg (NPIX x 36) ----------------
__global__ __launch_bounds__(256) void k_convC() {
    int t = threadIdx.x;
    int l = t & 63;
    int quad = l >> 4;
    int tile = blockIdx.x * 4 + (t >> 6);
    int m0 = tile * 16;
    int mA = min(m0 + (l & 15), NPIX - 1);
    int py = mA / F2, px = mA - py * F2;

    f32x4 acc0 = {0.0f, 0.0f, 0.0f, 0.0f};
    f32x4 acc1 = {0.0f, 0.0f, 0.0f, 0.0f};
    f32x4 acc2 = {0.0f, 0.0f, 0.0f, 0.0f};

    int kt = 0;
#pragma unroll
    for (int ky = 0; ky < 3; ++ky) {
#pragma unroll
        for (int kx = 0; kx < 3; ++kx) {
            const unsigned short* ap =
                g_feats + ((size_t)(py + ky) * 256 + (px + kx)) * 128 + quad * 8;
#pragma unroll
            for (int kc = 0; kc < 4; ++kc) {
                bf16x8 a = *(const bf16x8*)(ap + kc * 32);
                const unsigned short* bp = g_W2s + (size_t)kt * 1536 + l * 8;
                bf16x8 b0 = *(const bf16x8*)(bp);
                bf16x8 b1 = *(const bf16x8*)(bp + 512);
                bf16x8 b2v = *(const bf16x8*)(bp + 1024);
                acc0 = __builtin_amdgcn_mfma_f32_16x16x32_bf16(a, b0, acc0, 0, 0, 0);
                acc1 = __builtin_amdgcn_mfma_f32_16x16x32_bf16(a, b1, acc1, 0, 0, 0);
                acc2 = __builtin_amdgcn_mfma_f32_16x16x32_bf16(a, b2v, acc2, 0, 0, 0);
                ++kt;
            }
        }
    }

    int n0 = l & 15;
    int mB = m0 + quad * 4;
#pragma unroll
    for (int nt = 0; nt < 3; ++nt) {
        int n = nt * 16 + n0;
        if (n >= 45) continue;
        float bias = g_b2[n];
        f32x4 av = (nt == 0) ? acc0 : (nt == 1) ? acc1 : acc2;
#pragma unroll
        for (int r = 0; r < 4; ++r) {
            int m = mB + r;
            if (m < NPIX) {
                float vv = av[r] + bias;
                if (n < 9) g_cls[(size_t)m * 9 + n] = f2b(vv);
                else       g_reg[(size_t)m * 36 + (n - 9)] = f2b(vv);
            }
        }
    }
}

// ---------------- gt-max: early-out on outside, registers only, 16 atomics/block ----------------
__global__ __launch_bounds__(256) void k_gtmax(const float* __restrict__ gt) {
    __shared__ float red[4][KGT];
    int t = threadIdx.x;
    float m16[KGT];
#pragma unroll
    for (int k = 0; k < KGT; ++k) m16[k] = -1.0f;
    for (int n = blockIdx.x * 256 + t; n < NANCH; n += 256 * 256) {
        float v[KGT];
        if (anchor_ious(n, gt, v)) {
#pragma unroll
            for (int k = 0; k < KGT; ++k) m16[k] = fmaxf(m16[k], v[k]);
        }
    }
#pragma unroll
    for (int k = 0; k < KGT; ++k) {
#pragma unroll
        for (int m = 32; m; m >>= 1) m16[k] = fmaxf(m16[k], __shfl_xor(m16[k], m, 64));
    }
    int lane = t & 63, wv = t >> 6;
    if (lane == 0) {
#pragma unroll
        for (int k = 0; k < KGT; ++k) red[wv][k] = m16[k];
    }
    __syncthreads();
    if (t < KGT) {
        float mx = fmaxf(fmaxf(red[0][t], red[1][t]), fmaxf(red[2][t], red[3][t]));
        unsigned u = __float_as_uint(mx);
        unsigned key = (u & 0x80000000u) ? ~u : (u | 0x80000000u);
        atomicMax(&g_keys[t], key);
    }
}

// ---------------- loss: early-out on outside, registers only ----------------
__global__ __launch_bounds__(256) void k_loss(const float* __restrict__ gt) {
    __shared__ float red[4][4];
    int t = threadIdx.x;
    int n = blockIdx.x * 256 + t;
    float sb = 0.0f, ss = 0.0f, sx = 0.0f, sp = 0.0f;
    if (n < NANCH) {
        float v[KGT];
        bool inside = anchor_ious(n, gt, v);
        if (inside) {
            float maxi = -1.0f;
            bool best = false;
#pragma unroll
            for (int k = 0; k < KGT; ++k) {
                maxi = fmaxf(maxi, v[k]);
                unsigned e = g_keys[k];
                float gm = __uint_as_float((e & 0x80000000u) ? (e & 0x7FFFFFFFu) : ~e);
                best = best || (v[k] == gm);
            }
            bool ispos = best || (maxi >= 0.5f);
            float c = b2f(g_cls[n]);
            float z = ispos ? -c : c;
            sb = fmaxf(z, 0.0f) + log1pf(expf(-fabsf(z))); // softplus(z)
            ss = 1.0f;
            if (ispos) {
                ushort4 rh = *(const ushort4*)(g_reg + (size_t)n * 4);
                float aa;
                aa = fabsf(b2f(rh.x)); sx += (aa < 1.0f) ? 0.5f * aa * aa : aa - 0.5f;
                aa = fabsf(b2f(rh.y)); sx += (aa < 1.0f) ? 0.5f * aa * aa : aa - 0.5f;
                aa = fabsf(b2f(rh.z)); sx += (aa < 1.0f) ? 0.5f * aa * aa : aa - 0.5f;
                aa = fabsf(b2f(rh.w)); sx += (aa < 1.0f) ? 0.5f * aa * aa : aa - 0.5f;
                sp = 1.0f;
            }
        }
    }
#pragma unroll
    for (int m = 32; m; m >>= 1) {
        sb += __shfl_xor(sb, m, 64);
        ss += __shfl_xor(ss, m, 64);
        sx += __shfl_xor(sx, m, 64);
        sp += __shfl_xor(sp, m, 64);
    }
    int lane = t & 63, wv = t >> 6;
    if (lane == 0) { red[wv][0] = sb; red[wv][1] = ss; red[wv][2] = sx; red[wv][3] = sp; }
    __syncthreads();
    if (t < 4) {
        float s = red[0][t] + red[1][t] + red[2][t] + red[3][t];
        atomicAdd(&g_acc[t], s);
    }
}

// ---------------- finalize: dual-format store (bf16 exact in low16) ----------------
__global__ void k_fin(unsigned* out) {
    float res = g_acc[0] / g_acc[1] + g_acc[2] / g_acc[3];
    unsigned lo = (unsigned)f2b(res);
    unsigned hi = __float_as_uint(res) >> 16;
    out[0] = (hi << 16) | lo;
}

extern "C" void kernel_launch(void* const* d_in, const int* in_sizes, int n_in,
                              void* d_out, int out_size, void* d_ws, size_t ws_size,
                              hipStream_t stream) {
    (void)in_sizes; (void)n_in; (void)out_size; (void)d_ws; (void)ws_size;
    const float* image = (const float*)d_in[0];
    const float* gt    = (const float*)d_in[1];
    const float* Wb    = (const float*)d_in[2];
    const float* bb    = (const float*)d_in[3];
    const float* Wi    = (const float*)d_in[4];
    const float* bi    = (const float*)d_in[5];
    const float* Wc    = (const float*)d_in[6];
    const float* bc    = (const float*)d_in[7];
    const float* Wr    = (const float*)d_in[8];
    const float* br    = (const float*)d_in[9];

    k_init <<<1, 64, 0, stream>>>((unsigned*)d_out);
    k_conv1<<<1024, 256, 0, stream>>>(image, Wb, bb);
    k_w2   <<<217, 256, 0, stream>>>(Wi, bi, Wc, bc, Wr, br);
    k_convC<<<1009, 256, 0, stream>>>();
    k_gtmax<<<256, 256, 0, stream>>>(gt);
    k_loss <<<2269, 256, 0, stream>>>(gt);
    k_fin  <<<1, 1, 0, stream>>>((unsigned*)d_out);
}

// Round 11
// 187.556 us; speedup vs baseline: 2.8966x; 1.0804x over previous
//
#include <hip/hip_runtime.h>

// ---------------- problem constants ----------------
#define F2      254
#define NPIX    (F2 * F2)        // 64516 conv2 output pixels
#define NANCH   (NPIX * 9)       // 580644 anchors
#define KGT     16
#define GWC     (1.0f / 1024.0f) // gw == gh == 1/IMG

typedef __attribute__((ext_vector_type(8))) short bf16x8;
typedef __attribute__((ext_vector_type(4))) float f32x4;

// ---------------- static device storage ----------------
__device__ unsigned short g_feats[256 * 256 * 128];  // conv1 out, bf16, 16.78 MB
__device__ unsigned short g_cls[NPIX * 9];           // cls logits bf16
__device__ unsigned short g_reg[NPIX * 36];          // reg preds bf16
__device__ unsigned short g_W2s[36 * 3 * 64 * 8];    // combined weights, bf16, MFMA-B swizzled
__device__ float          g_b2[48];
__device__ float          g_acc[4];                  // bce_sum, sel_cnt, box_sum, pos_cnt
__device__ unsigned       g_keys[KGT];               // monotone-encoded gt-max

__device__ __forceinline__ float b2f(unsigned short h) {
    return __uint_as_float(((unsigned)h) << 16);
}
__device__ __forceinline__ unsigned short f2b(float f) {
    unsigned u = __float_as_uint(f);
    unsigned r = (u + 0x7FFFu + ((u >> 16) & 1u)) >> 16;
    return (unsigned short)r;
}

// ---------------- IoU core, fully inlined + unrolled: v[] stays in VGPRs ----------------
__device__ __forceinline__ bool anchor_ious(int n, const float* __restrict__ gt,
                                            float* __restrict__ v) {
    int w_idx = n / (F2 * 9);
    int rem = n - w_idx * (F2 * 9);
    int h_idx = rem / 9;
    int a = rem - h_idx * 9;
    int ri = a / 3, si = a - ri * 3;
    float rat = (ri == 0) ? 0.5f : (ri == 1) ? 1.0f : 2.0f;
    float scl = (si == 0) ? 0.2f : (si == 1) ? 0.4f : 0.7f;
    float rs = sqrtf(rat);
    float hw = scl * rs * 0.5f;
    float hh = scl / rs * 0.5f;
    float cx = (float)w_idx * (1.0f / 254.0f);
    float cy = (float)h_idx * (1.0f / 254.0f);
    float x1 = cx - hw, y1 = cy - hh, x2 = cx + hw, y2 = cy + hh;
    bool inside = (x1 >= 0.0f) && (y1 >= 0.0f) && (x2 < 1.0f) && (y2 < 1.0f);
    if (!inside) return false;
    float s1 = (x2 - x1 + GWC) * (y2 - y1 + GWC);
#pragma unroll
    for (int k = 0; k < KGT; ++k) {
        float gx1 = gt[k * 4 + 0], gy1 = gt[k * 4 + 1];
        float gx2 = gt[k * 4 + 2], gy2 = gt[k * 4 + 3];
        float s2 = (gx2 - gx1 + GWC) * (gy2 - gy1 + GWC);
        float xa = fmaxf(x1, gx1), ya = fmaxf(y1, gy1);
        float xb = fminf(x2, gx2), yb = fminf(y2, gy2);
        float iw = fmaxf(xb - xa + GWC, 0.0f);
        float ih = fmaxf(yb - ya + GWC, 0.0f);
        float inter = iw * ih;
        v[k] = inter / (s1 + s2 - inter);
    }
    return true;
}

// ---------------- conv1: wave = 64 pixels x 32 oc; weights via wave-uniform SCALAR loads ----------------
__global__ __launch_bounds__(256) void k_conv1(const float* __restrict__ img,
                                               const float* __restrict__ Wb,
                                               const float* __restrict__ bb) {
    int t = threadIdx.x;
    int lane = t & 63;
    int wave = __builtin_amdgcn_readfirstlane(t >> 6);
    int ocb = wave * 32;
    int p = blockIdx.x * 64 + lane;
    int oy = p >> 8, ox = p & 255;
    const float* ib = img + ((size_t)oy * 4 * 1024 + (size_t)ox * 4) * 3;

    float4 acc[8];
#pragma unroll
    for (int j = 0; j < 8; ++j) acc[j] = *(const float4*)(bb + ocb + j * 4);

#pragma unroll
    for (int r = 0; r < 4; ++r) {
        float4 p0 = *(const float4*)(ib + (size_t)r * 3072);
        float4 p1 = *(const float4*)(ib + (size_t)r * 3072 + 4);
        float4 p2 = *(const float4*)(ib + (size_t)r * 3072 + 8);
        float px[12] = {p0.x, p0.y, p0.z, p0.w, p1.x, p1.y, p1.z, p1.w, p2.x, p2.y, p2.z, p2.w};
#pragma unroll
        for (int q = 0; q < 12; ++q) {
            const float* wr = Wb + (size_t)(r * 12 + q) * 128 + ocb;  // wave-uniform -> s_load
#pragma unroll
            for (int j = 0; j < 8; ++j) {
                float4 w = *(const float4*)(wr + j * 4);
                acc[j].x = fmaf(px[q], w.x, acc[j].x);
                acc[j].y = fmaf(px[q], w.y, acc[j].y);
                acc[j].z = fmaf(px[q], w.z, acc[j].z);
                acc[j].w = fmaf(px[q], w.w, acc[j].w);
            }
        }
    }
#pragma unroll
    for (int j = 0; j < 8; ++j) {
        ushort4 o;
        o.x = f2b(acc[j].x); o.y = f2b(acc[j].y); o.z = f2b(acc[j].z); o.w = f2b(acc[j].w);
        *(ushort4*)(g_feats + (size_t)p * 128 + ocb + j * 4) = o;
    }
}

// ---------------- W2 precombine v2 (+ merged init): LDS-staged Wcr, wave-uniform Wi rows ----------------
// 288 blocks x 256 thr; block b computes k rows 4b..4b+3 (k wave-uniform -> s_load Wi row);
// lane = o reads LDS stride-1 (2-way alias, free). Same fp32 FMA order per (k,o) as before.
__global__ __launch_bounds__(256) void k_w2(const float* __restrict__ Wi,
                                            const float* __restrict__ bi,
                                            const float* __restrict__ Wc,
                                            const float* __restrict__ bc,
                                            const float* __restrict__ Wr,
                                            const float* __restrict__ br,
                                            unsigned* out) {
    __shared__ float wcr[256][48];   // 48 KB
    int t = threadIdx.x;
    int b = blockIdx.x;
    if (b == 0) {                    // merged k_init
        if (t < 4) g_acc[t] = 0.0f;
        if (t >= 4 && t < 4 + KGT) g_keys[t - 4] = 0x407FFFFFu; // enc(-1.0f)
        if (t == 32) out[0] = 0x3F803F80u;
    }
    for (int i = t; i < 2304; i += 256) wcr[i / 9][i % 9] = Wc[i];
    for (int i = t; i < 9216; i += 256) wcr[i / 36][9 + i % 36] = Wr[i];
    for (int i = t; i < 768; i += 256) wcr[i / 3][45 + i % 3] = 0.0f;
    __syncthreads();

    int wave = __builtin_amdgcn_readfirstlane(t >> 6);
    int lane = t & 63;
    int k = b * 4 + wave;            // 0..1151
    int o = min(lane, 47);
    const float* wik = Wi + (size_t)k * 256;
    float acc = 0.0f;
#pragma unroll 8
    for (int oc = 0; oc < 256; ++oc)
        acc = fmaf(wik[oc], wcr[oc][o], acc);

    if (lane < 48) {
        int kt = k >> 5, r5 = k & 31, j = r5 & 7, lhi = r5 >> 3;
        int nt = o >> 4, llo = o & 15, l = lhi * 16 + llo;
        g_W2s[(size_t)((kt * 3 + nt) * 64 + l) * 8 + j] = f2b(acc);
    }
    if (b == 0 && t < 48) {
        float a2 = (t < 9) ? bc[t] : ((t < 45) ? br[t - 9] : 0.0f);
        for (int oc = 0; oc < 256; ++oc) a2 = fmaf(bi[oc], wcr[oc][t], a2);
        g_b2[t] = a2;
    }
}

// ---------------- combined conv via MFMA, 2 M-tiles/wave: feats -> cls, reg ----------------
// Wave = 32 pixels x 48 outputs; B fragments shared across both A fragments (halves B traffic).
__global__ __launch_bounds__(256) void k_convC() {
    int t = threadIdx.x;
    int l = t & 63;
    int quad = l >> 4;
    int tile = blockIdx.x * 4 + (t >> 6);
    int m0 = tile * 32;
    int mA0 = min(m0 + (l & 15), NPIX - 1);
    int mA1 = min(m0 + 16 + (l & 15), NPIX - 1);
    int py0 = mA0 / F2, px0 = mA0 - py0 * F2;
    int py1 = mA1 / F2, px1 = mA1 - py1 * F2;

    f32x4 acc[2][3];
#pragma unroll
    for (int h = 0; h < 2; ++h)
#pragma unroll
        for (int nt = 0; nt < 3; ++nt) acc[h][nt] = (f32x4){0.0f, 0.0f, 0.0f, 0.0f};

    int kt = 0;
#pragma unroll
    for (int ky = 0; ky < 3; ++ky) {
#pragma unroll
        for (int kx = 0; kx < 3; ++kx) {
            const unsigned short* ap0 =
                g_feats + ((size_t)(py0 + ky) * 256 + (px0 + kx)) * 128 + quad * 8;
            const unsigned short* ap1 =
                g_feats + ((size_t)(py1 + ky) * 256 + (px1 + kx)) * 128 + quad * 8;
#pragma unroll
            for (int kc = 0; kc < 4; ++kc) {
                bf16x8 a0 = *(const bf16x8*)(ap0 + kc * 32);
                bf16x8 a1 = *(const bf16x8*)(ap1 + kc * 32);
                const unsigned short* bp = g_W2s + (size_t)kt * 1536 + l * 8;
                bf16x8 b0 = *(const bf16x8*)(bp);
                bf16x8 b1 = *(const bf16x8*)(bp + 512);
                bf16x8 b2v = *(const bf16x8*)(bp + 1024);
                acc[0][0] = __builtin_amdgcn_mfma_f32_16x16x32_bf16(a0, b0, acc[0][0], 0, 0, 0);
                acc[0][1] = __builtin_amdgcn_mfma_f32_16x16x32_bf16(a0, b1, acc[0][1], 0, 0, 0);
                acc[0][2] = __builtin_amdgcn_mfma_f32_16x16x32_bf16(a0, b2v, acc[0][2], 0, 0, 0);
                acc[1][0] = __builtin_amdgcn_mfma_f32_16x16x32_bf16(a1, b0, acc[1][0], 0, 0, 0);
                acc[1][1] = __builtin_amdgcn_mfma_f32_16x16x32_bf16(a1, b1, acc[1][1], 0, 0, 0);
                acc[1][2] = __builtin_amdgcn_mfma_f32_16x16x32_bf16(a1, b2v, acc[1][2], 0, 0, 0);
                ++kt;
            }
        }
    }

    int n0 = l & 15;
#pragma unroll
    for (int h = 0; h < 2; ++h) {
        int mB = m0 + h * 16 + quad * 4;
#pragma unroll
        for (int nt = 0; nt < 3; ++nt) {
            int n = nt * 16 + n0;
            if (n >= 45) continue;
            float bias = g_b2[n];
#pragma unroll
            for (int r = 0; r < 4; ++r) {
                int m = mB + r;
                if (m < NPIX) {
                    float vv = acc[h][nt][r] + bias;
                    if (n < 9) g_cls[(size_t)m * 9 + n] = f2b(vv);
                    else       g_reg[(size_t)m * 36 + (n - 9)] = f2b(vv);
                }
            }
        }
    }
}

// ---------------- gt-max: early-out on outside, registers only, 16 atomics/block ----------------
__global__ __launch_bounds__(256) void k_gtmax(const float* __restrict__ gt) {
    __shared__ float red[4][KGT];
    int t = threadIdx.x;
    float m16[KGT];
#pragma unroll
    for (int k = 0; k < KGT; ++k) m16[k] = -1.0f;
    for (int n = blockIdx.x * 256 + t; n < NANCH; n += 256 * 256) {
        float v[KGT];
        if (anchor_ious(n, gt, v)) {
#pragma unroll
            for (int k = 0; k < KGT; ++k) m16[k] = fmaxf(m16[k], v[k]);
        }
    }
#pragma unroll
    for (int k = 0; k < KGT; ++k) {
#pragma unroll
        for (int m = 32; m; m >>= 1) m16[k] = fmaxf(m16[k], __shfl_xor(m16[k], m, 64));
    }
    int lane = t & 63, wv = t >> 6;
    if (lane == 0) {
#pragma unroll
        for (int k = 0; k < KGT; ++k) red[wv][k] = m16[k];
    }
    __syncthreads();
    if (t < KGT) {
        float mx = fmaxf(fmaxf(red[0][t], red[1][t]), fmaxf(red[2][t], red[3][t]));
        unsigned u = __float_as_uint(mx);
        unsigned key = (u & 0x80000000u) ? ~u : (u | 0x80000000u);
        atomicMax(&g_keys[t], key);
    }
}

// ---------------- loss: early-out on outside, registers only ----------------
__global__ __launch_bounds__(256) void k_loss(const float* __restrict__ gt) {
    __shared__ float red[4][4];
    int t = threadIdx.x;
    int n = blockIdx.x * 256 + t;
    float sb = 0.0f, ss = 0.0f, sx = 0.0f, sp = 0.0f;
    if (n < NANCH) {
        float v[KGT];
        bool inside = anchor_ious(n, gt, v);
        if (inside) {
            float maxi = -1.0f;
            bool best = false;
#pragma unroll
            for (int k = 0; k < KGT; ++k) {
                maxi = fmaxf(maxi, v[k]);
                unsigned e = g_keys[k];
                float gm = __uint_as_float((e & 0x80000000u) ? (e & 0x7FFFFFFFu) : ~e);
                best = best || (v[k] == gm);
            }
            bool ispos = best || (maxi >= 0.5f);
            float c = b2f(g_cls[n]);
            float z = ispos ? -c : c;
            sb = fmaxf(z, 0.0f) + log1pf(expf(-fabsf(z))); // softplus(z)
            ss = 1.0f;
            if (ispos) {
                ushort4 rh = *(const ushort4*)(g_reg + (size_t)n * 4);
                float aa;
                aa = fabsf(b2f(rh.x)); sx += (aa < 1.0f) ? 0.5f * aa * aa : aa - 0.5f;
                aa = fabsf(b2f(rh.y)); sx += (aa < 1.0f) ? 0.5f * aa * aa : aa - 0.5f;
                aa = fabsf(b2f(rh.z)); sx += (aa < 1.0f) ? 0.5f * aa * aa : aa - 0.5f;
                aa = fabsf(b2f(rh.w)); sx += (aa < 1.0f) ? 0.5f * aa * aa : aa - 0.5f;
                sp = 1.0f;
            }
        }
    }
#pragma unroll
    for (int m = 32; m; m >>= 1) {
        sb += __shfl_xor(sb, m, 64);
        ss += __shfl_xor(ss, m, 64);
        sx += __shfl_xor(sx, m, 64);
        sp += __shfl_xor(sp, m, 64);
    }
    int lane = t & 63, wv = t >> 6;
    if (lane == 0) { red[wv][0] = sb; red[wv][1] = ss; red[wv][2] = sx; red[wv][3] = sp; }
    __syncthreads();
    if (t < 4) {
        float s = red[0][t] + red[1][t] + red[2][t] + red[3][t];
        atomicAdd(&g_acc[t], s);
    }
}

// ---------------- finalize: dual-format store (bf16 exact in low16) ----------------
__global__ void k_fin(unsigned* out) {
    float res = g_acc[0] / g_acc[1] + g_acc[2] / g_acc[3];
    unsigned lo = (unsigned)f2b(res);
    unsigned hi = __float_as_uint(res) >> 16;
    out[0] = (hi << 16) | lo;
}

extern "C" void kernel_launch(void* const* d_in, const int* in_sizes, int n_in,
                              void* d_out, int out_size, void* d_ws, size_t ws_size,
                              hipStream_t stream) {
    (void)in_sizes; (void)n_in; (void)out_size; (void)d_ws; (void)ws_size;
    const float* image = (const float*)d_in[0];
    const float* gt    = (const float*)d_in[1];
    const float* Wb    = (const float*)d_in[2];
    const float* bb    = (const float*)d_in[3];
    const float* Wi    = (const float*)d_in[4];
    const float* bi    = (const float*)d_in[5];
    const float* Wc    = (const float*)d_in[6];
    const float* bc    = (const float*)d_in[7];
    const float* Wr    = (const float*)d_in[8];
    const float* br    = (const float*)d_in[9];

    k_w2   <<<288, 256, 0, stream>>>(Wi, bi, Wc, bc, Wr, br, (unsigned*)d_out);
    k_conv1<<<1024, 256, 0, stream>>>(image, Wb, bb);
    k_convC<<<505, 256, 0, stream>>>();
    k_gtmax<<<256, 256, 0, stream>>>(gt);
    k_loss <<<2269, 256, 0, stream>>>(gt);
    k_fin  <<<1, 1, 0, stream>>>((unsigned*)d_out);
}